// Round 1
// baseline (224.766 us; speedup 1.0000x reference)
//
#include <hip/hip_runtime.h>

// 9x9 box filter (r=4), reflect padding, 24 planes of 2048x2048 f32.
// Memory-bound: target 1 read + 1 write per pixel (plus 12.5% vertical halo).
// No LDS, no barriers: horizontal 9-sum via sliding window in registers,
// vertical 9-sum via 9-deep circular register buffer (phase static via
// unroll-by-9 so no scratch spill).

constexpr int H   = 2048;
constexpr int W   = 2048;
constexpr int RH  = 64;    // output rows per block; RH+8 = 72 = 8*9 (no tail)
constexpr int R   = 4;     // radius (hard-coded; reference setup uses r=4)
constexpr int TPB = 256;   // one full row per block: 256 threads * 8 cols

__global__ __launch_bounds__(TPB) void BoxFilter_kernel(
    const float* __restrict__ x, float* __restrict__ out) {
  const int t     = threadIdx.x;
  const int bid   = blockIdx.x;
  const int plane = bid >> 5;        // H/RH == 32 chunks
  const int chunk = bid & 31;
  const int r0    = chunk * RH;
  const float* __restrict__ px = x   + (size_t)plane * H * W;
  float*       __restrict__ po = out + (size_t)plane * H * W;
  const int c0 = t << 3;             // this thread's first output column

  float hbuf[9][8];                  // circular history of horizontal sums
  float vsum[8];                     // running vertical sum of last 9 h-rows
#pragma unroll
  for (int j = 0; j < 8; ++j) vsum[j] = 0.0f;
#pragma unroll
  for (int p = 0; p < 9; ++p)
#pragma unroll
    for (int j = 0; j < 8; ++j) hbuf[p][j] = 0.0f;

  const float inv81 = 1.0f / 81.0f;

  for (int s0 = 0; s0 < RH + 2 * R; s0 += 9) {
#pragma unroll
    for (int p = 0; p < 9; ++p) {    // p is compile-time after unroll
      const int s = s0 + p;
      int lr = r0 - R + s;           // input row for this step (reflect)
      lr = (lr < 0) ? -lr : lr;
      lr = (lr >= H) ? (2 * H - 2 - lr) : lr;
      const float* __restrict__ row = px + (size_t)lr * W;

      // v[i] = row[c0 - 4 + i], i = 0..15 (covers windows of 8 outputs)
      float v[16];
      if (t == 0) {
        // cols -4..-1 reflect to 4,3,2,1
        v[0] = row[4]; v[1] = row[3]; v[2] = row[2]; v[3] = row[1];
        float4 a = *(const float4*)(row + 0);
        float4 b = *(const float4*)(row + 4);
        float4 c = *(const float4*)(row + 8);
        v[4]  = a.x; v[5]  = a.y; v[6]  = a.z; v[7]  = a.w;
        v[8]  = b.x; v[9]  = b.y; v[10] = b.z; v[11] = b.w;
        v[12] = c.x; v[13] = c.y; v[14] = c.z; v[15] = c.w;
      } else if (t == TPB - 1) {
        const float* base = row + (c0 - R);   // col 2036, 16B aligned
        float4 a = *(const float4*)(base + 0);
        float4 b = *(const float4*)(base + 4);
        float4 c = *(const float4*)(base + 8);
        v[0]  = a.x; v[1]  = a.y; v[2]  = a.z; v[3]  = a.w;
        v[4]  = b.x; v[5]  = b.y; v[6]  = b.z; v[7]  = b.w;
        v[8]  = c.x; v[9]  = c.y; v[10] = c.z; v[11] = c.w;
        // cols 2048..2051 reflect to 2046,2045,2044,2043
        v[12] = row[W - 2]; v[13] = row[W - 3];
        v[14] = row[W - 4]; v[15] = row[W - 5];
      } else {
        const float* base = row + (c0 - R);   // byte addr 32t-16: 16B aligned
        float4 a = *(const float4*)(base + 0);
        float4 b = *(const float4*)(base + 4);
        float4 c = *(const float4*)(base + 8);
        float4 d = *(const float4*)(base + 12);
        v[0]  = a.x; v[1]  = a.y; v[2]  = a.z; v[3]  = a.w;
        v[4]  = b.x; v[5]  = b.y; v[6]  = b.z; v[7]  = b.w;
        v[8]  = c.x; v[9]  = c.y; v[10] = c.z; v[11] = c.w;
        v[12] = d.x; v[13] = d.y; v[14] = d.z; v[15] = d.w;
      }

      // horizontal sliding 9-sums: h[j] = sum(v[j..j+8])
      float h[8];
      h[0] = ((v[0] + v[1]) + (v[2] + v[3])) +
             ((v[4] + v[5]) + (v[6] + v[7])) + v[8];
#pragma unroll
      for (int j = 1; j < 8; ++j) h[j] = h[j - 1] + v[j + 8] - v[j - 1];

      // vertical running sum over last 9 h-rows (hbuf starts zeroed)
#pragma unroll
      for (int j = 0; j < 8; ++j) {
        vsum[j]    += h[j] - hbuf[p][j];
        hbuf[p][j]  = h[j];
      }

      if (s >= 2 * R) {              // block-uniform branch
        const int orow = r0 + s - 2 * R;   // always within [r0, r0+RH)
        float* o = po + (size_t)orow * W + c0;
        float4 o0 = make_float4(vsum[0] * inv81, vsum[1] * inv81,
                                vsum[2] * inv81, vsum[3] * inv81);
        float4 o1 = make_float4(vsum[4] * inv81, vsum[5] * inv81,
                                vsum[6] * inv81, vsum[7] * inv81);
        *(float4*)(o + 0) = o0;
        *(float4*)(o + 4) = o1;
      }
    }
  }
}

extern "C" void kernel_launch(void* const* d_in, const int* in_sizes, int n_in,
                              void* d_out, int out_size, void* d_ws, size_t ws_size,
                              hipStream_t stream) {
  const float* x  = (const float*)d_in[0];
  float*       out = (float*)d_out;
  const int planes = out_size / (H * W);        // 8*3 = 24
  dim3 grid(planes * (H / RH));                 // 24 * 32 = 768 blocks
  dim3 block(TPB);
  hipLaunchKernelGGL(BoxFilter_kernel, grid, block, 0, stream, x, out);
}

// Round 2
// 207.360 us; speedup vs baseline: 1.0839x; 1.0839x over previous
//
#include <hip/hip_runtime.h>

// 9x9 box filter (r=4), reflect padding, 24 planes of 2048x2048 f32.
// Latency-bound fix (R1): RH 64->32 doubles the grid (1536 blocks = 6/CU =
// 24 waves/CU static occupancy) so TLP covers HBM latency. Phase-static
// circular buffer: step s uses hbuf[s%9]; row loop = 4 full groups of 9 +
// compile-time tail of 4, so every phase index is a literal (no scratch).
// Non-temporal stores keep L2 for input halo reuse.

constexpr int H     = 2048;
constexpr int W     = 2048;
constexpr int RH    = 32;            // output rows per block
constexpr int R     = 4;             // radius (reference uses r=4)
constexpr int TPB   = 256;           // one full row: 256 threads * 8 cols
constexpr int STEPS = RH + 2 * R;    // 40
constexpr int FULLG = (STEPS / 9) * 9;  // 36
constexpr int TAIL  = STEPS - FULLG;    // 4

typedef float f32x4 __attribute__((ext_vector_type(4)));

template <int P>
__device__ __forceinline__ void bf_step(
    int s, int r0, int t, int c0,
    const float* __restrict__ px, float* __restrict__ po,
    float (&hbuf)[9][8], float (&vsum)[8]) {
  int lr = r0 - R + s;               // input row (reflect)
  lr = (lr < 0) ? -lr : lr;
  lr = (lr >= H) ? (2 * H - 2 - lr) : lr;
  const float* __restrict__ row = px + (size_t)lr * W;

  // v[i] = row[c0 - 4 + i], i = 0..15 (covers windows of 8 outputs)
  float v[16];
  if (t == 0) {
    // cols -4..-1 reflect to 4,3,2,1
    v[0] = row[4]; v[1] = row[3]; v[2] = row[2]; v[3] = row[1];
    float4 a = *(const float4*)(row + 0);
    float4 b = *(const float4*)(row + 4);
    float4 c = *(const float4*)(row + 8);
    v[4]  = a.x; v[5]  = a.y; v[6]  = a.z; v[7]  = a.w;
    v[8]  = b.x; v[9]  = b.y; v[10] = b.z; v[11] = b.w;
    v[12] = c.x; v[13] = c.y; v[14] = c.z; v[15] = c.w;
  } else if (t == TPB - 1) {
    const float* base = row + (c0 - R);   // col 2036, 16B aligned
    float4 a = *(const float4*)(base + 0);
    float4 b = *(const float4*)(base + 4);
    float4 c = *(const float4*)(base + 8);
    v[0]  = a.x; v[1]  = a.y; v[2]  = a.z; v[3]  = a.w;
    v[4]  = b.x; v[5]  = b.y; v[6]  = b.z; v[7]  = b.w;
    v[8]  = c.x; v[9]  = c.y; v[10] = c.z; v[11] = c.w;
    // cols 2048..2051 reflect to 2046,2045,2044,2043
    v[12] = row[W - 2]; v[13] = row[W - 3];
    v[14] = row[W - 4]; v[15] = row[W - 5];
  } else {
    const float* base = row + (c0 - R);   // byte addr 32t-16: 16B aligned
    float4 a = *(const float4*)(base + 0);
    float4 b = *(const float4*)(base + 4);
    float4 c = *(const float4*)(base + 8);
    float4 d = *(const float4*)(base + 12);
    v[0]  = a.x; v[1]  = a.y; v[2]  = a.z; v[3]  = a.w;
    v[4]  = b.x; v[5]  = b.y; v[6]  = b.z; v[7]  = b.w;
    v[8]  = c.x; v[9]  = c.y; v[10] = c.z; v[11] = c.w;
    v[12] = d.x; v[13] = d.y; v[14] = d.z; v[15] = d.w;
  }

  // horizontal sliding 9-sums: h[j] = sum(v[j..j+8])
  float h[8];
  h[0] = ((v[0] + v[1]) + (v[2] + v[3])) +
         ((v[4] + v[5]) + (v[6] + v[7])) + v[8];
#pragma unroll
  for (int j = 1; j < 8; ++j) h[j] = h[j - 1] + v[j + 8] - v[j - 1];

  // vertical running sum over last 9 h-rows (hbuf starts zeroed); phase = P
#pragma unroll
  for (int j = 0; j < 8; ++j) {
    vsum[j]    += h[j] - hbuf[P][j];
    hbuf[P][j]  = h[j];
  }

  if (s >= 2 * R) {                  // block-uniform branch
    const float inv81 = 1.0f / 81.0f;
    const int orow = r0 + s - 2 * R; // always within [r0, r0+RH)
    float* o = po + (size_t)orow * W + c0;
    f32x4 o0 = {vsum[0] * inv81, vsum[1] * inv81,
                vsum[2] * inv81, vsum[3] * inv81};
    f32x4 o1 = {vsum[4] * inv81, vsum[5] * inv81,
                vsum[6] * inv81, vsum[7] * inv81};
    __builtin_nontemporal_store(o0, (f32x4*)(o + 0));
    __builtin_nontemporal_store(o1, (f32x4*)(o + 4));
  }
}

__global__ __launch_bounds__(TPB) void BoxFilter_kernel(
    const float* __restrict__ x, float* __restrict__ out) {
  const int t     = threadIdx.x;
  const int bid   = blockIdx.x;
  const int plane = bid >> 6;        // H/RH == 64 chunks per plane
  const int chunk = bid & 63;
  const int r0    = chunk * RH;
  const float* __restrict__ px = x   + (size_t)plane * H * W;
  float*       __restrict__ po = out + (size_t)plane * H * W;
  const int c0 = t << 3;             // this thread's first output column

  float hbuf[9][8];                  // circular history of horizontal sums
  float vsum[8];                     // running vertical sum of last 9 h-rows
#pragma unroll
  for (int j = 0; j < 8; ++j) vsum[j] = 0.0f;
#pragma unroll
  for (int p = 0; p < 9; ++p)
#pragma unroll
    for (int j = 0; j < 8; ++j) hbuf[p][j] = 0.0f;

  for (int s0 = 0; s0 < FULLG; s0 += 9) {
    bf_step<0>(s0 + 0, r0, t, c0, px, po, hbuf, vsum);
    bf_step<1>(s0 + 1, r0, t, c0, px, po, hbuf, vsum);
    bf_step<2>(s0 + 2, r0, t, c0, px, po, hbuf, vsum);
    bf_step<3>(s0 + 3, r0, t, c0, px, po, hbuf, vsum);
    bf_step<4>(s0 + 4, r0, t, c0, px, po, hbuf, vsum);
    bf_step<5>(s0 + 5, r0, t, c0, px, po, hbuf, vsum);
    bf_step<6>(s0 + 6, r0, t, c0, px, po, hbuf, vsum);
    bf_step<7>(s0 + 7, r0, t, c0, px, po, hbuf, vsum);
    bf_step<8>(s0 + 8, r0, t, c0, px, po, hbuf, vsum);
  }
  // tail: steps FULLG .. STEPS-1, phase = s % 9 = s - FULLG (FULLG % 9 == 0)
  static_assert(TAIL == 4, "tail unroll below assumes 4 steps");
  bf_step<0>(FULLG + 0, r0, t, c0, px, po, hbuf, vsum);
  bf_step<1>(FULLG + 1, r0, t, c0, px, po, hbuf, vsum);
  bf_step<2>(FULLG + 2, r0, t, c0, px, po, hbuf, vsum);
  bf_step<3>(FULLG + 3, r0, t, c0, px, po, hbuf, vsum);
}

extern "C" void kernel_launch(void* const* d_in, const int* in_sizes, int n_in,
                              void* d_out, int out_size, void* d_ws, size_t ws_size,
                              hipStream_t stream) {
  const float* x   = (const float*)d_in[0];
  float*       out = (float*)d_out;
  const int planes = out_size / (H * W);        // 8*3 = 24
  dim3 grid(planes * (H / RH));                 // 24 * 64 = 1536 blocks
  dim3 block(TPB);
  hipLaunchKernelGGL(BoxFilter_kernel, grid, block, 0, stream, x, out);
}